// Round 4
// baseline (53.665 us; speedup 1.0000x reference)
//
#include <hip/hip_runtime.h>
#include <hip/hip_bf16.h>

// out[i] = mask[i] ? x[i] * (1/(1-0.5)) : 0
// x: float32, mask: int32 (verified R2, absmax=0). Pure 2-read+1-write
// stream, 308.3 MB/call -> memory-bound. R2: 52.9 us = 5.82 TB/s (92.5% of
// achievable). This round: non-temporal hints via clang ext_vector types
// (HIP_vector_type float4 is a class -> builtin rejects it; R3 compile fail).

typedef float  f32x4 __attribute__((ext_vector_type(4)));
typedef int    i32x4 __attribute__((ext_vector_type(4)));

__global__ void __launch_bounds__(256)
dropout_vec4_nt_kernel(const f32x4* __restrict__ x4,
                       const i32x4* __restrict__ m4,
                       f32x4* __restrict__ o4,
                       int n4)
{
    const float scale = 2.0f;  // 1 / (1 - 0.5)
    int idx = blockIdx.x * blockDim.x + threadIdx.x;
    int stride = gridDim.x * blockDim.x;
    for (int i = idx; i < n4; i += stride) {
        f32x4 xv = __builtin_nontemporal_load(&x4[i]);
        i32x4 mv = __builtin_nontemporal_load(&m4[i]);
        f32x4 ov;
        ov.x = mv.x ? xv.x * scale : 0.0f;
        ov.y = mv.y ? xv.y * scale : 0.0f;
        ov.z = mv.z ? xv.z * scale : 0.0f;
        ov.w = mv.w ? xv.w * scale : 0.0f;
        __builtin_nontemporal_store(ov, &o4[i]);
    }
}

// Scalar tail (not expected to run: 25,690,112 % 4 == 0).
__global__ void __launch_bounds__(256)
dropout_tail_kernel(const float* __restrict__ x,
                    const int* __restrict__ m,
                    float* __restrict__ o,
                    int start, int n)
{
    int i = start + blockIdx.x * blockDim.x + threadIdx.x;
    if (i < n) {
        o[i] = m[i] ? x[i] * 2.0f : 0.0f;
    }
}

extern "C" void kernel_launch(void* const* d_in, const int* in_sizes, int n_in,
                              void* d_out, int out_size, void* d_ws, size_t ws_size,
                              hipStream_t stream)
{
    const float* x = (const float*)d_in[0];
    const int*   m = (const int*)d_in[1];
    float*       o = (float*)d_out;

    int n  = out_size;      // 25,690,112
    int n4 = n / 4;

    const int block = 256;
    int grid = (n4 + block - 1) / block;
    if (grid > 2048) grid = 2048;
    if (grid < 1) grid = 1;

    dropout_vec4_nt_kernel<<<grid, block, 0, stream>>>(
        (const f32x4*)x, (const i32x4*)m, (f32x4*)o, n4);

    int rem = n - n4 * 4;
    if (rem > 0) {
        int tgrid = (rem + block - 1) / block;
        dropout_tail_kernel<<<tgrid, block, 0, stream>>>(x, m, o, n4 * 4, n);
    }
}